// Round 10
// baseline (986.807 us; speedup 1.0000x reference)
//
#include <hip/hip_runtime.h>
#include <hip/hip_bf16.h>
#include <hip/hip_cooperative_groups.h>

namespace cg = cooperative_groups;

typedef __attribute__((ext_vector_type(8))) short short8;
typedef __attribute__((ext_vector_type(4))) float floatx4;

__device__ __forceinline__ ushort f2bf(float x) {
    __hip_bfloat16 h = __float2bfloat16(x);
    return __builtin_bit_cast(ushort, h);
}
__device__ __forceinline__ float bf2f(ushort u) {
    __hip_bfloat16 h = __builtin_bit_cast(__hip_bfloat16, u);
    return __bfloat162float(h);
}

// fast tanh: 1 - 2/(e^{2z}+1); v_exp + v_rcp, ~1e-6 abs err
__device__ __forceinline__ float fast_tanh(float z) {
    float e = __expf(2.0f * z);
    return 1.0f - 2.0f * __builtin_amdgcn_rcpf(e + 1.0f);
}

// async global -> LDS, 16 bytes per lane. LDS dest is wave-uniform base + lane*16;
// per-lane GLOBAL source is arbitrary (exploited for the XOR bank swizzle).
__device__ __forceinline__ void gload_lds16(const ushort* g, ushort* l) {
    __builtin_amdgcn_global_load_lds(
        (const __attribute__((address_space(1))) unsigned int*)(const void*)g,
        (__attribute__((address_space(3))) unsigned int*)(void*)l,
        16, 0, 0);
}

// ---------------------------------------------------------------------------
// ONE persistent cooperative kernel, 256 blocks x 512 threads (1 block/CU,
// 128 KB LDS -> exact co-residency). Phases separated by grid.sync():
//   P : h0 pack (grid-stride, 64 float4/thread) + 3 weight transposes
//   G0: h1 = h0 + 0.1*tanh(h0@Wf+bf)      (512 jobs, 2/block)
//   G1: h2 = h1 + 0.1*tanh(h1@Wf+bf)
//   G2: g  = relu(h2@W1+b1)
//   G3: out= tanh(g@W2+b2)                (256 jobs, 1/block, fp32 out)
// GEMM phase body = Round-7's MEASURED schedule, byte-identical:
//   256x256 tile, 8 waves (2Mx4N), acc[8][4], ring-4 of 32-k panels,
//   2 barriers/panel (phase a barrier-free), counted vmcnt(8), setprio(1)
//   around MFMA clusters, XOR bank swizzle (0 conflicts measured).
// Job decode preserves id&7 XCD affinity (jobs = bid, bid+256; 256 % 8 == 0).
// Runtime phase table (mode/NOUT/nxlog/pointers) -> ONE copy of panel code.
// ---------------------------------------------------------------------------
__global__ __launch_bounds__(512, 2) void fused(
    const float* __restrict__ inp, const float* __restrict__ hz,
    const float* __restrict__ Wf,  const float* __restrict__ W1,
    const float* __restrict__ W2,  const float* __restrict__ bfb,
    const float* __restrict__ b1,  const float* __restrict__ b2,
    ushort* __restrict__ WfT, ushort* __restrict__ W1T, ushort* __restrict__ W2T,
    ushort* __restrict__ bufA, ushort* __restrict__ bufB, float* __restrict__ out)
{
    __shared__ ushort As[4][8192];   // 64 KB ring (also overlaid as transpose tile)
    __shared__ ushort Bs[4][8192];   // 64 KB ring

    cg::grid_group grid = cg::this_grid();
    const int tid = threadIdx.x;
    const int bid = blockIdx.x;
    const int wave = tid >> 6, lane = tid & 63;

    // ================= phase P: pack + transposes =================
    {
        // pack: 8,388,608 float4 items (inp then hz), 64 per thread
        int u = bid * 512 + tid;
        #pragma unroll 2
        for (int it = 0; it < 64; ++it, u += 131072) {
            const int isHz = (u >= 4194304) ? 1 : 0;
            const float* src = isHz ? hz : inp;
            const int v = isHz ? (u - 4194304) : u;
            const size_t i = (size_t)v * 4;           // fp32 index in [32768][512]
            const size_t row = i >> 9;
            const int col = (int)(i & 511);
            float4 x = *(const float4*)(src + i);
            ushort4 o = make_ushort4(f2bf(x.x), f2bf(x.y), f2bf(x.z), f2bf(x.w));
            *(ushort4*)(bufA + row * 1024 + isHz * 512 + col) = o;
        }
        // transposes: 2560 32x32-tile jobs (Wf 1024, W1 1024, W2 512), 10/block
        float* tl = (float*)&As[0][0];               // [32][33] fp32 overlay
        const int tx = tid & 31, ty = tid >> 5;      // ty 0..15
        for (int t = bid; t < 2560; t += 256) {
            int t2 = t; const float* W; ushort* WT; int N = 1024;
            if (t2 < 1024)      { W = Wf; WT = WfT; }
            else if (t2 < 2048) { W = W1; WT = W1T; t2 -= 1024; }
            else                { W = W2; WT = W2T; t2 -= 2048; N = 512; }
            const int nb = (t2 % (N / 32)) * 32, kb = (t2 / (N / 32)) * 32;
            __syncthreads();                          // tile reuse guard
            #pragma unroll
            for (int j = ty; j < 32; j += 16)
                tl[j * 33 + tx] = W[(size_t)(kb + j) * N + nb + tx];
            __syncthreads();
            #pragma unroll
            for (int j = ty; j < 32; j += 16)
                WT[(size_t)(nb + j) * 1024 + kb + tx] = f2bf(tl[tx * 33 + j]);
        }
    }
    __threadfence();
    grid.sync();

    // ================= GEMM phases (R7 panel schedule) =================
    const int waveM = wave >> 2;      // 0..1  (128-row band)
    const int waveN = wave & 3;       // 0..3  (64-col band)
    const int c = wave * 64 + lane;   // 0..511 staging slot
    const int ra = c >> 2;            // 0..127
    const int qa = (c & 3) ^ ((ra >> 1) & 3);
    const int mrow = lane & 15;
    const int g = lane >> 4;                  // logical k-quad
    const int pq = g ^ ((mrow >> 1) & 3);     // physical quad
    ushort* asD = &As[0][0] + wave * 512;
    ushort* bsD = &Bs[0][0] + wave * 512;
    const ushort* aB = &As[0][0] + (waveM * 128 + mrow) * 32 + pq * 8;
    const ushort* bB = &Bs[0][0] + (waveN * 64 + mrow) * 32 + pq * 8;

#define MFMA_ROW(MT, AF)                                                            \
    acc[MT][0] = __builtin_amdgcn_mfma_f32_16x16x32_bf16(AF, bf0, acc[MT][0], 0,0,0); \
    acc[MT][1] = __builtin_amdgcn_mfma_f32_16x16x32_bf16(AF, bf1, acc[MT][1], 0,0,0); \
    acc[MT][2] = __builtin_amdgcn_mfma_f32_16x16x32_bf16(AF, bf2, acc[MT][2], 0,0,0); \
    acc[MT][3] = __builtin_amdgcn_mfma_f32_16x16x32_bf16(AF, bf3, acc[MT][3], 0,0,0);

#define PANEL(T, STG, VMASM)                                                   \
  {                                                                            \
    const int s  = (T) & 3;                                                    \
    const int s3 = ((T) + 3) & 3;                                              \
    /* phase a (barrier-free): frags rows 0..63 + A staging */                 \
    short8 af0 = *(const short8*)(aB + s * 8192 + 0 * 512);                    \
    short8 af1 = *(const short8*)(aB + s * 8192 + 1 * 512);                    \
    short8 af2 = *(const short8*)(aB + s * 8192 + 2 * 512);                    \
    short8 af3 = *(const short8*)(aB + s * 8192 + 3 * 512);                    \
    short8 bf0 = *(const short8*)(bB + s * 8192 + 0 * 512);                    \
    short8 bf1 = *(const short8*)(bB + s * 8192 + 1 * 512);                    \
    short8 bf2 = *(const short8*)(bB + s * 8192 + 2 * 512);                    \
    short8 bf3 = *(const short8*)(bB + s * 8192 + 3 * 512);                    \
    if (STG) {                                                                 \
      gload_lds16(agA0 + ((T) + 3) * 32, asD + s3 * 8192);                     \
      gload_lds16(agA1 + ((T) + 3) * 32, asD + s3 * 8192 + 4096);              \
    }                                                                          \
    asm volatile("s_waitcnt lgkmcnt(0)" ::: "memory");                         \
    __builtin_amdgcn_sched_barrier(0);                                         \
    __builtin_amdgcn_s_setprio(1);                                             \
    MFMA_ROW(0, af0) MFMA_ROW(1, af1) MFMA_ROW(2, af2) MFMA_ROW(3, af3)        \
    __builtin_amdgcn_s_setprio(0);                                             \
    /* phase b: frags rows 64..127 (bfr reused) + B staging */                 \
    af0 = *(const short8*)(aB + s * 8192 + 2048 + 0 * 512);                    \
    af1 = *(const short8*)(aB + s * 8192 + 2048 + 1 * 512);                    \
    af2 = *(const short8*)(aB + s * 8192 + 2048 + 2 * 512);                    \
    af3 = *(const short8*)(aB + s * 8192 + 2048 + 3 * 512);                    \
    if (STG) {                                                                 \
      gload_lds16(bgB0 + ((T) + 3) * 32, bsD + s3 * 8192);                     \
      gload_lds16(bgB1 + ((T) + 3) * 32, bsD + s3 * 8192 + 4096);              \
    }                                                                          \
    asm volatile(VMASM ::: "memory");                                          \
    __builtin_amdgcn_s_barrier();      /* OPEN: availability broadcast */      \
    asm volatile("s_waitcnt lgkmcnt(0)" ::: "memory");                         \
    __builtin_amdgcn_sched_barrier(0);                                         \
    __builtin_amdgcn_s_setprio(1);                                             \
    MFMA_ROW(4, af0) MFMA_ROW(5, af1) MFMA_ROW(6, af2) MFMA_ROW(7, af3)        \
    __builtin_amdgcn_s_setprio(0);                                             \
    __builtin_amdgcn_sched_barrier(0);                                         \
    __builtin_amdgcn_s_barrier();      /* CLOSE: slot-reuse protection */      \
  }

    for (int ph = 0; ph < 4; ++ph) {
        const ushort* Ap; const ushort* BTp; const float* biasp;
        ushort* oB; float* oF; int mode, NOUT, nxlog, nJobs;
        if (ph == 0)      { Ap = bufA; BTp = WfT; biasp = bfb; oB = bufB; oF = nullptr; mode = 1; NOUT = 1024; nxlog = 2; nJobs = 512; }
        else if (ph == 1) { Ap = bufB; BTp = WfT; biasp = bfb; oB = bufA; oF = nullptr; mode = 1; NOUT = 1024; nxlog = 2; nJobs = 512; }
        else if (ph == 2) { Ap = bufA; BTp = W1T; biasp = b1;  oB = bufB; oF = nullptr; mode = 2; NOUT = 1024; nxlog = 2; nJobs = 512; }
        else              { Ap = bufB; BTp = W2T; biasp = b2;  oB = nullptr; oF = out;  mode = 3; NOUT = 512;  nxlog = 1; nJobs = 256; }

        for (int job = bid; job < nJobs; job += 256) {
            const int inner = job >> 3;
            const int nTile = inner & ((1 << nxlog) - 1);
            const int mTile = (job & 7) * 16 + (inner >> nxlog);
            const int mBase = mTile * 256;
            const int nBase = nTile * 256;

            const ushort* agA0 = Ap  + (size_t)(mBase + ra) * 1024 + qa * 8;
            const ushort* agA1 = Ap  + (size_t)(mBase + 128 + ra) * 1024 + qa * 8;
            const ushort* bgB0 = BTp + (size_t)(nBase + ra) * 1024 + qa * 8;
            const ushort* bgB1 = BTp + (size_t)(nBase + 128 + ra) * 1024 + qa * 8;

            floatx4 acc[8][4];
            #pragma unroll
            for (int i = 0; i < 8; i++)
                #pragma unroll
                for (int j = 0; j < 4; j++) acc[i][j] = (floatx4)(0.f);

            // prologue: stage panels 0..2; vmcnt(8) -> panel 0 landed
            #pragma unroll
            for (int p = 0; p < 3; ++p) {
                gload_lds16(agA0 + p * 32, asD + p * 8192);
                gload_lds16(agA1 + p * 32, asD + p * 8192 + 4096);
                gload_lds16(bgB0 + p * 32, bsD + p * 8192);
                gload_lds16(bgB1 + p * 32, bsD + p * 8192 + 4096);
            }
            asm volatile("s_waitcnt vmcnt(8)" ::: "memory");
            __builtin_amdgcn_s_barrier();

            // main loop: 28 panels, steady-state vmcnt(8); 4-body period
            for (int tt = 0; tt < 7; ++tt) {
                const int t4 = tt * 4;
                PANEL(t4 + 0, true, "s_waitcnt vmcnt(8)")
                PANEL(t4 + 1, true, "s_waitcnt vmcnt(8)")
                PANEL(t4 + 2, true, "s_waitcnt vmcnt(8)")
                PANEL(t4 + 3, true, "s_waitcnt vmcnt(8)")
            }
            // graded tail
            PANEL(28, true,  "s_waitcnt vmcnt(8)")
            PANEL(29, false, "s_waitcnt vmcnt(4)")
            PANEL(30, false, "s_waitcnt vmcnt(0)")
            PANEL(31, false, "s_waitcnt vmcnt(0)")

            // epilogue: C/D layout col=lane&15, row=(lane>>4)*4+reg [m89/m91]
            const int col0 = nBase + waveN * 64 + (lane & 15);
            const int row0 = mBase + waveM * 128 + (lane >> 4) * 4;
            #pragma unroll
            for (int mt = 0; mt < 8; mt++) {
                #pragma unroll
                for (int nt = 0; nt < 4; nt++) {
                    const int col = col0 + nt * 16;
                    const float bv = biasp[col];
                    #pragma unroll
                    for (int r = 0; r < 4; r++) {
                        const int row = row0 + mt * 16 + r;
                        const float z = acc[mt][nt][r] + bv;
                        if (mode == 1) {
                            float carry = bf2f(Ap[(size_t)row * 1024 + col]);
                            oB[(size_t)row * NOUT + col] = f2bf(carry + 0.1f * fast_tanh(z));
                        } else if (mode == 2) {
                            oB[(size_t)row * NOUT + col] = f2bf(fmaxf(z, 0.f));
                        } else {
                            oF[(size_t)row * NOUT + col] = fast_tanh(z);
                        }
                    }
                }
            }
        }
        __threadfence();
        grid.sync();
    }
#undef PANEL
#undef MFMA_ROW
}

extern "C" void kernel_launch(void* const* d_in, const int* in_sizes, int n_in,
                              void* d_out, int out_size, void* d_ws, size_t ws_size,
                              hipStream_t stream) {
    const float* inp = (const float*)d_in[0];  // [32,1024,512]
    const float* hz  = (const float*)d_in[1];  // [32,1024,512]
    const float* Wf  = (const float*)d_in[2];  // [1024,1024]
    const float* bf_ = (const float*)d_in[3];  // [1024]
    const float* W1  = (const float*)d_in[4];  // [1024,1024]
    const float* b1  = (const float*)d_in[5];  // [1024]
    const float* W2  = (const float*)d_in[6];  // [1024,512]
    const float* b2  = (const float*)d_in[7];  // [512]
    float* out = (float*)d_out;                // [32,1024,512] fp32

    char* ws = (char*)d_ws;
    ushort* WfT  = (ushort*)(ws);                                  // 2 MB
    ushort* W1T  = (ushort*)(ws + (size_t)(2 << 20));              // 2 MB
    ushort* W2T  = (ushort*)(ws + (size_t)(4 << 20));              // 1 MB
    ushort* bufA = (ushort*)(ws + (size_t)(8 << 20));              // 64 MB
    ushort* bufB = (ushort*)(ws + (size_t)(8 << 20) + ((size_t)64 << 20));  // 64 MB

    void* args[] = { (void*)&inp, (void*)&hz, (void*)&Wf, (void*)&W1, (void*)&W2,
                     (void*)&bf_, (void*)&b1, (void*)&b2,
                     (void*)&WfT, (void*)&W1T, (void*)&W2T,
                     (void*)&bufA, (void*)&bufB, (void*)&out };
    hipLaunchCooperativeKernel((const void*)fused, dim3(256), dim3(512),
                               args, 0, stream);
}

// Round 11
// 444.552 us; speedup vs baseline: 2.2198x; 2.2198x over previous
//
#include <hip/hip_runtime.h>
#include <hip/hip_bf16.h>

typedef __attribute__((ext_vector_type(8))) short short8;
typedef __attribute__((ext_vector_type(4))) float floatx4;

__device__ __forceinline__ ushort f2bf(float x) {
    __hip_bfloat16 h = __float2bfloat16(x);
    return __builtin_bit_cast(ushort, h);
}
__device__ __forceinline__ float bf2f(ushort u) {
    __hip_bfloat16 h = __builtin_bit_cast(__hip_bfloat16, u);
    return __bfloat162float(h);
}

// fast tanh: 1 - 2/(e^{2z}+1); v_exp + v_rcp, ~1e-6 abs err
__device__ __forceinline__ float fast_tanh(float z) {
    float e = __expf(2.0f * z);
    return 1.0f - 2.0f * __builtin_amdgcn_rcpf(e + 1.0f);
}

// async global -> LDS, 16 bytes per lane. LDS dest is wave-uniform base + lane*16;
// per-lane GLOBAL source is arbitrary (exploited for the XOR bank swizzle).
__device__ __forceinline__ void gload_lds16(const ushort* g, ushort* l) {
    __builtin_amdgcn_global_load_lds(
        (const __attribute__((address_space(1))) unsigned int*)(const void*)g,
        (__attribute__((address_space(3))) unsigned int*)(void*)l,
        16, 0, 0);
}

// ---------------------------------------------------------------------------
// Fused prep, ONE dispatch, 18944 blocks x 256 threads.
//   blocks [0,16384):   h0 pack — each thread converts 8 consecutive fp32
//                       (2x float4 load, 32B/lane) to one short8 store
//                       (16B/lane — coalescing sweet spot, was 8B).
//   blocks [16384,...): 3 weight transposes, 32x32 LDS tile; store phase
//                       emits ONE ushort4 (8B) per thread covering 4
//                       k-columns (was 4x 2-byte scalar stores).
// ---------------------------------------------------------------------------
__global__ void prep(const float* __restrict__ inp, const float* __restrict__ hz,
                     const float* __restrict__ Wf, const float* __restrict__ W1,
                     const float* __restrict__ W2,
                     ushort* __restrict__ h0, ushort* __restrict__ WfT,
                     ushort* __restrict__ W1T, ushort* __restrict__ W2T) {
    int bid = blockIdx.x;
    int tid = threadIdx.x;
    __shared__ float tile[32][33];
    if (bid < 16384) {
        // 4,194,304 chunks of 8 fp32 over [inp | hz] (2,097,152 each)
        int u = bid * 256 + tid;
        const int isHz = (u >= 2097152) ? 1 : 0;
        const float* src = isHz ? hz : inp;
        const int v = u - isHz * 2097152;
        const size_t i = (size_t)v * 8;           // fp32 index in [32768][512]
        const size_t row = i >> 9;
        const int col = (int)(i & 511);           // col % 8 == 0
        float4 x0 = *(const float4*)(src + i);
        float4 x1 = *(const float4*)(src + i + 4);
        short8 o;
        o[0] = (short)f2bf(x0.x); o[1] = (short)f2bf(x0.y);
        o[2] = (short)f2bf(x0.z); o[3] = (short)f2bf(x0.w);
        o[4] = (short)f2bf(x1.x); o[5] = (short)f2bf(x1.y);
        o[6] = (short)f2bf(x1.z); o[7] = (short)f2bf(x1.w);
        *(short8*)(h0 + row * 1024 + isHz * 512 + col) = o;
    } else {
        int t = bid - 16384;
        const float* W;
        ushort* WT;
        int N = 1024;
        if (t < 1024)      { W = Wf; WT = WfT; }
        else if (t < 2048) { W = W1; WT = W1T; t -= 1024; }
        else               { W = W2; WT = W2T; t -= 2048; N = 512; }
        const int tx = tid & 31, ty = tid >> 5;   // ty 0..7
        const int nb = (t % (N / 32)) * 32, kb = (t / (N / 32)) * 32;
        #pragma unroll
        for (int j = ty; j < 32; j += 8)
            tile[j][tx] = W[(size_t)(kb + j) * N + nb + tx];   // tile[k][n]
        __syncthreads();
        // store: thread -> out-row nb+j2 (n), 4 k-cols kb+kc..kc+3, one ushort4
        const int j2 = tid >> 3;            // 0..31
        const int kc = (tid & 7) * 4;       // 0..28
        ushort4 o = make_ushort4(f2bf(tile[kc][j2]),     f2bf(tile[kc + 1][j2]),
                                 f2bf(tile[kc + 2][j2]), f2bf(tile[kc + 3][j2]));
        *(ushort4*)(WT + (size_t)(nb + j2) * 1024 + kb + kc) = o;
    }
}

// ---------------------------------------------------------------------------
// 256x256-tile bf16 MFMA GEMM, 512 threads / 8 waves (2M x 4N), per-wave
// output 128x64 (acc[8][4]). Ring-4 of 32-k panels.  (Round-7 MEASURED
// schedule, byte-identical: 82.8us/dispatch, MfmaUtil 35.6%, 0 conflicts.)
//
// SYNC STRUCTURE: 2 barriers per panel, both in phase b. Phase a is
// barrier-free (own-data lgkmcnt(0) only). Hazard ledger in R5/R6 notes.
// Per-wave vmcnt ledger: 4 gloads/panel, vmcnt(8) retires panel t+1;
// tail grades 8 -> 4 -> 0 -> 0.
//
// MODE 1: out_bf = bf2f(A[row][col]) + 0.1*tanh(acc + bias)   (euler step)
// MODE 2: out_bf = relu(acc + bias)
// MODE 3: out_f32 = tanh(acc + bias)
// Grid 1-D: xcd=id&7 owns 16 M-tiles; N-tiles innermost for L2 A-reuse.
// ---------------------------------------------------------------------------
template <int MODE, int NOUT, int NX>
__global__ __launch_bounds__(512, 2) void gemm_ep(
    const ushort* __restrict__ A, const ushort* __restrict__ BT,
    const float* __restrict__ bias,
    ushort* __restrict__ outB, float* __restrict__ outF) {
    constexpr int K = 1024;
    __shared__ ushort As[4][8192];   // 4 slots x 256 rows x 32 k = 64 KB
    __shared__ ushort Bs[4][8192];   // 64 KB

    const int tid = threadIdx.x;
    const int wave = tid >> 6, lane = tid & 63;

    const int id = blockIdx.x;
    const int inner = id >> 3;
    const int nTile = inner % NX;
    const int mTile = (id & 7) * 16 + inner / NX;   // 128 M-tiles / 8 XCDs
    const int mBase = mTile * 256;
    const int nBase = nTile * 256;
    const int waveM = wave >> 2;      // 0..1  (128-row band)
    const int waveN = wave & 3;       // 0..3  (64-col band)

    // Staging: physical 16B slot c holds logical (row r=c>>2, quad
    // q=(c&3)^((r>>1)&3)) within a 128-row half; halves at +4096 ushorts.
    const int c = wave * 64 + lane;           // 0..511
    const int ra = c >> 2;                    // 0..127
    const int qa = (c & 3) ^ ((ra >> 1) & 3);
    const ushort* agA0 = A  + (size_t)(mBase + ra) * K + qa * 8;
    const ushort* agA1 = A  + (size_t)(mBase + 128 + ra) * K + qa * 8;
    const ushort* bgB0 = BT + (size_t)(nBase + ra) * K + qa * 8;
    const ushort* bgB1 = BT + (size_t)(nBase + 128 + ra) * K + qa * 8;
    ushort* asD = &As[0][0] + wave * 512;
    ushort* bsD = &Bs[0][0] + wave * 512;

    floatx4 acc[8][4];
    #pragma unroll
    for (int i = 0; i < 8; i++)
        #pragma unroll
        for (int j = 0; j < 4; j++) acc[i][j] = (floatx4)(0.f);

    const int mrow = lane & 15;
    const int g = lane >> 4;                  // logical k-quad
    const int pq = g ^ ((mrow >> 1) & 3);     // physical quad
    const ushort* aB = &As[0][0] + (waveM * 128 + mrow) * 32 + pq * 8;
    const ushort* bB = &Bs[0][0] + (waveN * 64 + mrow) * 32 + pq * 8;

#define MFMA_ROW(MT, AF)                                                            \
    acc[MT][0] = __builtin_amdgcn_mfma_f32_16x16x32_bf16(AF, bf0, acc[MT][0], 0,0,0); \
    acc[MT][1] = __builtin_amdgcn_mfma_f32_16x16x32_bf16(AF, bf1, acc[MT][1], 0,0,0); \
    acc[MT][2] = __builtin_amdgcn_mfma_f32_16x16x32_bf16(AF, bf2, acc[MT][2], 0,0,0); \
    acc[MT][3] = __builtin_amdgcn_mfma_f32_16x16x32_bf16(AF, bf3, acc[MT][3], 0,0,0);

#define PANEL(T, STG, VMASM)                                                   \
  {                                                                            \
    const int s  = (T) & 3;                                                    \
    const int s3 = ((T) + 3) & 3;                                              \
    /* phase a (barrier-free): frags rows 0..63 + A staging */                 \
    short8 af0 = *(const short8*)(aB + s * 8192 + 0 * 512);                    \
    short8 af1 = *(const short8*)(aB + s * 8192 + 1 * 512);                    \
    short8 af2 = *(const short8*)(aB + s * 8192 + 2 * 512);                    \
    short8 af3 = *(const short8*)(aB + s * 8192 + 3 * 512);                    \
    short8 bf0 = *(const short8*)(bB + s * 8192 + 0 * 512);                    \
    short8 bf1 = *(const short8*)(bB + s * 8192 + 1 * 512);                    \
    short8 bf2 = *(const short8*)(bB + s * 8192 + 2 * 512);                    \
    short8 bf3 = *(const short8*)(bB + s * 8192 + 3 * 512);                    \
    if (STG) {                                                                 \
      gload_lds16(agA0 + ((T) + 3) * 32, asD + s3 * 8192);                     \
      gload_lds16(agA1 + ((T) + 3) * 32, asD + s3 * 8192 + 4096);              \
    }                                                                          \
    asm volatile("s_waitcnt lgkmcnt(0)" ::: "memory");                         \
    __builtin_amdgcn_sched_barrier(0);                                         \
    __builtin_amdgcn_s_setprio(1);                                             \
    MFMA_ROW(0, af0) MFMA_ROW(1, af1) MFMA_ROW(2, af2) MFMA_ROW(3, af3)        \
    __builtin_amdgcn_s_setprio(0);                                             \
    /* phase b: frags rows 64..127 (bfr reused) + B staging */                 \
    af0 = *(const short8*)(aB + s * 8192 + 2048 + 0 * 512);                    \
    af1 = *(const short8*)(aB + s * 8192 + 2048 + 1 * 512);                    \
    af2 = *(const short8*)(aB + s * 8192 + 2048 + 2 * 512);                    \
    af3 = *(const short8*)(aB + s * 8192 + 2048 + 3 * 512);                    \
    if (STG) {                                                                 \
      gload_lds16(bgB0 + ((T) + 3) * 32, bsD + s3 * 8192);                     \
      gload_lds16(bgB1 + ((T) + 3) * 32, bsD + s3 * 8192 + 4096);              \
    }                                                                          \
    asm volatile(VMASM ::: "memory");                                          \
    __builtin_amdgcn_s_barrier();      /* OPEN: availability broadcast */      \
    asm volatile("s_waitcnt lgkmcnt(0)" ::: "memory");                         \
    __builtin_amdgcn_sched_barrier(0);                                         \
    __builtin_amdgcn_s_setprio(1);                                             \
    MFMA_ROW(4, af0) MFMA_ROW(5, af1) MFMA_ROW(6, af2) MFMA_ROW(7, af3)        \
    __builtin_amdgcn_s_setprio(0);                                             \
    __builtin_amdgcn_sched_barrier(0);                                         \
    __builtin_amdgcn_s_barrier();      /* CLOSE: slot-reuse protection */      \
  }

    // prologue: stage panels 0..2; vmcnt(8) -> panel 0 landed
    #pragma unroll
    for (int p = 0; p < 3; ++p) {
        gload_lds16(agA0 + p * 32, asD + p * 8192);
        gload_lds16(agA1 + p * 32, asD + p * 8192 + 4096);
        gload_lds16(bgB0 + p * 32, bsD + p * 8192);
        gload_lds16(bgB1 + p * 32, bsD + p * 8192 + 4096);
    }
    asm volatile("s_waitcnt vmcnt(8)" ::: "memory");
    __builtin_amdgcn_s_barrier();

    // main loop: 28 panels with steady-state vmcnt(8); explicit 4-body period
    // so (t&3) folds to compile-time slot constants.
    for (int tt = 0; tt < 7; ++tt) {
        const int t4 = tt * 4;
        PANEL(t4 + 0, true, "s_waitcnt vmcnt(8)")
        PANEL(t4 + 1, true, "s_waitcnt vmcnt(8)")
        PANEL(t4 + 2, true, "s_waitcnt vmcnt(8)")
        PANEL(t4 + 3, true, "s_waitcnt vmcnt(8)")
    }
    // graded tail: 28 stages panel 31; 29/30 drain; 31 clean
    PANEL(28, true,  "s_waitcnt vmcnt(8)")
    PANEL(29, false, "s_waitcnt vmcnt(4)")
    PANEL(30, false, "s_waitcnt vmcnt(0)")
    PANEL(31, false, "s_waitcnt vmcnt(0)")

#undef PANEL
#undef MFMA_ROW

    // epilogue: C/D layout col=lane&15, row=(lane>>4)*4+reg  [m89/m91]
    const int col0 = nBase + waveN * 64 + (lane & 15);
    const int row0 = mBase + waveM * 128 + (lane >> 4) * 4;
    #pragma unroll
    for (int mt = 0; mt < 8; mt++) {
        #pragma unroll
        for (int nt = 0; nt < 4; nt++) {
            const int col = col0 + nt * 16;
            const float bv = bias[col];
            #pragma unroll
            for (int r = 0; r < 4; r++) {
                const int row = row0 + mt * 16 + r;
                const float z = acc[mt][nt][r] + bv;
                if (MODE == 1) {
                    float carry = bf2f(A[(size_t)row * K + col]);
                    outB[(size_t)row * NOUT + col] = f2bf(carry + 0.1f * fast_tanh(z));
                } else if (MODE == 2) {
                    outB[(size_t)row * NOUT + col] = f2bf(fmaxf(z, 0.f));
                } else {
                    outF[(size_t)row * NOUT + col] = fast_tanh(z);
                }
            }
        }
    }
}

extern "C" void kernel_launch(void* const* d_in, const int* in_sizes, int n_in,
                              void* d_out, int out_size, void* d_ws, size_t ws_size,
                              hipStream_t stream) {
    const float* inp = (const float*)d_in[0];  // [32,1024,512]
    const float* hz  = (const float*)d_in[1];  // [32,1024,512]
    const float* Wf  = (const float*)d_in[2];  // [1024,1024]
    const float* bf_ = (const float*)d_in[3];  // [1024]
    const float* W1  = (const float*)d_in[4];  // [1024,1024]
    const float* b1  = (const float*)d_in[5];  // [1024]
    const float* W2  = (const float*)d_in[6];  // [1024,512]
    const float* b2  = (const float*)d_in[7];  // [512]
    float* out = (float*)d_out;                // [32,1024,512] fp32

    char* ws = (char*)d_ws;
    ushort* WfT  = (ushort*)(ws);                                  // 2 MB
    ushort* W1T  = (ushort*)(ws + (size_t)(2 << 20));              // 2 MB
    ushort* W2T  = (ushort*)(ws + (size_t)(4 << 20));              // 1 MB
    ushort* bufA = (ushort*)(ws + (size_t)(8 << 20));              // 64 MB
    ushort* bufB = (ushort*)(ws + (size_t)(8 << 20) + ((size_t)64 << 20));  // 64 MB

    // fused prep: h0 pack (16384 blocks) + 3 weight transposes (2560 blocks)
    prep<<<18944, 256, 0, stream>>>(inp, hz, Wf, W1, W2, bufA, WfT, W1T, W2T);

    // h1 = h0 + 0.1*tanh(h0@Wf + bf)      (128 M-tiles x 4 N-tiles)
    gemm_ep<1, 1024, 4><<<512, 512, 0, stream>>>(bufA, WfT, bf_, bufB, nullptr);
    // h2 = h1 + 0.1*tanh(h1@Wf + bf)
    gemm_ep<1, 1024, 4><<<512, 512, 0, stream>>>(bufB, WfT, bf_, bufA, nullptr);
    // g = relu(h2@W1 + b1)
    gemm_ep<2, 1024, 4><<<512, 512, 0, stream>>>(bufA, W1T, b1, bufB, nullptr);
    // out = tanh(g@W2 + b2)               (128 M-tiles x 2 N-tiles)
    gemm_ep<3, 512, 2><<<256, 512, 0, stream>>>(bufB, W2T, b2, nullptr, out);
}